// Round 1
// baseline (804.338 us; speedup 1.0000x reference)
//
#include <hip/hip_runtime.h>
#include <cmath>

namespace {
constexpr int MSTEPS = 50000;
constexpr int NSYN   = 500;
constexpr int NQ4    = 125;    // NSYN / 4
constexpr int NTH    = 1024;
constexpr int TPT    = 49;     // NTH*TPT = 50176 >= MSTEPS
constexpr double DELTA_D = 1.0e-3;
constexpr double THETA_D = 1.0;
// float32(exp(-1/10)) promoted to double — match the reference's f32 decay constant
constexpr float DECAY_F = 0.90483741803595957311f;
constexpr int CROSS_NONE = 0x7fffffff;
}

// ---------------- Kernel 1: per-timestep weighted row sums ----------------
// sw[i] = sum_j |w_j| * spikes[i][j] ; iw[i] = sum_j vrev_j*|w_j| * spikes[i][j]
// One wave per row; float4 loads; double accumulate (minimize our-side rounding).
__global__ __launch_bounds__(256) void k_rowdot(
    const float* __restrict__ spikes,
    const float* __restrict__ w,
    const float* __restrict__ vrev,
    float* __restrict__ swv,
    float* __restrict__ iwv)
{
    const int lane = threadIdx.x & 63;
    const int wv   = threadIdx.x >> 6;
    const int row  = blockIdx.x * 4 + wv;
    if (row >= MSTEPS) return;
    const float4* __restrict__ srow = reinterpret_cast<const float4*>(spikes + (size_t)row * NSYN);
    const float4* __restrict__ w4   = reinterpret_cast<const float4*>(w);
    const float4* __restrict__ r4   = reinterpret_cast<const float4*>(vrev);
    double sp = 0.0, ip = 0.0;
    for (int j = lane; j < NQ4; j += 64) {
        float4 s = srow[j];
        float4 a = w4[j];
        float4 r = r4[j];
        double ax = fabs((double)a.x), ay = fabs((double)a.y);
        double az = fabs((double)a.z), aw = fabs((double)a.w);
        sp += (double)s.x * ax + (double)s.y * ay + (double)s.z * az + (double)s.w * aw;
        ip += (double)s.x * (ax * (double)r.x) + (double)s.y * (ay * (double)r.y)
            + (double)s.z * (az * (double)r.z) + (double)s.w * (aw * (double)r.w);
    }
#pragma unroll
    for (int d = 32; d > 0; d >>= 1) {
        sp += __shfl_down(sp, d);
        ip += __shfl_down(ip, d);
    }
    if (lane == 0) {
        swv[row] = (float)sp;
        iwv[row] = (float)ip;
    }
}

// ---------------- Kernel 2: scans + segment-hopping vtr ----------------
// Pass A: block affine scan -> g_sum/i_sum entry per thread chunk.
// Pass B: block scan of (p, q) with (p1,q1)o(p2,q2) = (p1*p2, q1 + q2/p1)
//         giving global prefix P_i = prod alpha, Q_i = sum b_k / P_{k+1}.
// Pass C: store (P_i, Q_i) per element (double2).
// Then wave 0 hops reset segments: v_i = P_i*(Q_i - Q_r), first i with v>=theta
// resets state to 0 (next index), matching the reference recurrence exactly.
__global__ __launch_bounds__(1024) void k_scan(
    const float* __restrict__ swv,
    const float* __restrict__ iwv,
    double2* __restrict__ pqa,
    float* __restrict__ out)
{
    const double decay = (double)DECAY_F;
    const int tid  = threadIdx.x;
    const int lane = tid & 63;
    const int wv   = tid >> 6;
    const int base = tid * TPT;

    __shared__ double s_a[16], s_b[16], s_c[16];

    // ---- Pass A: local (g,i) scan with zero entry ----
    double g = 0.0, ii = 0.0;
    for (int k = 0; k < TPT; ++k) {
        int idx = base + k;
        double s = (idx < MSTEPS) ? (double)swv[idx] : 0.0;
        double t = (idx < MSTEPS) ? (double)iwv[idx] : 0.0;
        g  = (g + s) * decay;
        ii = (ii + t) * decay;
    }
    double dm = 1.0;
    for (int k = 0; k < TPT; ++k) dm *= decay;   // decay^TPT (uniform all threads)

    // inclusive intra-wave affine scan of (m, g, i)
    double m_in = dm, g_in = g, i_in = ii;
#pragma unroll
    for (int d = 1; d < 64; d <<= 1) {
        double pm = __shfl_up(m_in, d);
        double pg = __shfl_up(g_in, d);
        double pi = __shfl_up(i_in, d);
        if (lane >= d) {
            g_in = m_in * pg + g_in;   // compose(prev, cur): uses cur.m before update
            i_in = m_in * pi + i_in;
            m_in = pm * m_in;
        }
    }
    if (lane == 63) { s_a[wv] = m_in; s_b[wv] = g_in; s_c[wv] = i_in; }
    __syncthreads();
    if (wv == 0) {
        double wm = (lane < 16) ? s_a[lane] : 1.0;
        double wg = (lane < 16) ? s_b[lane] : 0.0;
        double wi = (lane < 16) ? s_c[lane] : 0.0;
#pragma unroll
        for (int d = 1; d < 16; d <<= 1) {
            double pm = __shfl_up(wm, d);
            double pg = __shfl_up(wg, d);
            double pi = __shfl_up(wi, d);
            if (lane >= d) {
                wg = wm * pg + wg;
                wi = wm * pi + wi;
                wm = pm * wm;
            }
        }
        if (lane < 16) { s_a[lane] = wm; s_b[lane] = wg; s_c[lane] = wi; }
    }
    __syncthreads();
    // exclusive entry = waveprefix o intra_exclusive
    double em = __shfl_up(m_in, 1), eg = __shfl_up(g_in, 1), ei = __shfl_up(i_in, 1);
    if (lane == 0) { em = 1.0; eg = 0.0; ei = 0.0; }
    if (wv > 0) {
        double qm = s_a[wv - 1], qg = s_b[wv - 1], qi = s_c[wv - 1];
        eg = em * qg + eg;
        ei = em * qi + ei;
        em = qm * em;
    }
    const double gent = eg, ient = ei;
    __syncthreads();   // s_a..c reused below

    // ---- Pass B: local (p, q) with zero entry, then block scan ----
    g = gent; ii = ient;
    double p = 1.0, q = 0.0;
    for (int k = 0; k < TPT; ++k) {
        int idx = base + k;
        double aa = DELTA_D * (1.0 + g);
        double bb = DELTA_D * ii;
        p *= (1.0 - aa);
        q += bb / p;
        double s = (idx < MSTEPS) ? (double)swv[idx] : 0.0;
        double t = (idx < MSTEPS) ? (double)iwv[idx] : 0.0;
        g  = (g + s) * decay;
        ii = (ii + t) * decay;
    }
    double p_in = p, q_in = q;
#pragma unroll
    for (int d = 1; d < 64; d <<= 1) {
        double pp = __shfl_up(p_in, d);
        double pq = __shfl_up(q_in, d);
        if (lane >= d) {
            q_in = pq + q_in / pp;     // compose(prev, cur)
            p_in = pp * p_in;
        }
    }
    if (lane == 63) { s_a[wv] = p_in; s_b[wv] = q_in; }
    __syncthreads();
    if (wv == 0) {
        double wp = (lane < 16) ? s_a[lane] : 1.0;
        double wq = (lane < 16) ? s_b[lane] : 0.0;
#pragma unroll
        for (int d = 1; d < 16; d <<= 1) {
            double pp = __shfl_up(wp, d);
            double pq = __shfl_up(wq, d);
            if (lane >= d) {
                wq = pq + wq / pp;
                wp = pp * wp;
            }
        }
        if (lane < 16) { s_a[lane] = wp; s_b[lane] = wq; }
    }
    __syncthreads();
    double ep = __shfl_up(p_in, 1), eq = __shfl_up(q_in, 1);
    if (lane == 0) { ep = 1.0; eq = 0.0; }
    if (wv > 0) {
        double ap = s_a[wv - 1], aq = s_b[wv - 1];
        eq = aq + eq / ap;
        ep = ap * ep;
    }

    // ---- Pass C: store global (P_i, Q_i) ----
    g = gent; ii = ient;
    double P = ep, Q = eq;
    for (int k = 0; k < TPT; ++k) {
        int idx = base + k;
        if (idx < MSTEPS) pqa[idx] = make_double2(P, Q);
        double aa = DELTA_D * (1.0 + g);
        double bb = DELTA_D * ii;
        P *= (1.0 - aa);
        Q += bb / P;
        double s = (idx < MSTEPS) ? (double)swv[idx] : 0.0;
        double t = (idx < MSTEPS) ? (double)iwv[idx] : 0.0;
        g  = (g + s) * decay;
        ii = (ii + t) * decay;
    }
    __threadfence_block();
    __syncthreads();

    // ---- Segment loop: wave 0 only ----
    if (wv != 0) return;
    if (lane == 0) out[0] = 0.0f;
    double Qr = 0.0;   // Q[0] = 0 (reset base at index 0)
    int pos = 1;
    while (pos < MSTEPS) {
        int myc = CROSS_NONE;
#pragma unroll 4
        for (int k = 0; k < 32; ++k) {
            int i = pos + (k << 6) + lane;
            if (i < MSTEPS) {
                double2 pq = pqa[i];
                double v = pq.x * (pq.y - Qr);
                out[i] = (float)v;
                if (v >= THETA_D && myc == CROSS_NONE) myc = i;
            }
        }
#pragma unroll
        for (int d = 32; d > 0; d >>= 1) myc = min(myc, __shfl_down(myc, d));
        myc = __shfl(myc, 0);
        if (myc == CROSS_NONE) {
            pos += 2048;
        } else {
            int nb = myc + 1;        // v[nb] = 0 (reset after crossing at myc)
            if (nb < MSTEPS) {
                if (lane == 0) out[nb] = 0.0f;
                double2 pqb = pqa[nb];
                Qr = pqb.y;
                pos = nb + 1;
            } else {
                pos = MSTEPS;
            }
        }
    }
}

extern "C" void kernel_launch(void* const* d_in, const int* in_sizes, int n_in,
                              void* d_out, int out_size, void* d_ws, size_t ws_size,
                              hipStream_t stream) {
    const float* spikes = (const float*)d_in[0];
    const float* w      = (const float*)d_in[1];
    const float* vrev   = (const float*)d_in[2];
    float* out = (float*)d_out;

    // workspace layout: sw[50176] f32 | iw[50176] f32 | PQ[50000] double2
    float* swv = (float*)d_ws;
    float* iwv = swv + (NTH * TPT);
    double2* pqa = (double2*)((char*)d_ws + (size_t)2 * NTH * TPT * sizeof(float));

    hipLaunchKernelGGL(k_rowdot, dim3(MSTEPS / 4), dim3(256), 0, stream,
                       spikes, w, vrev, swv, iwv);
    hipLaunchKernelGGL(k_scan, dim3(1), dim3(NTH), 0, stream,
                       swv, iwv, pqa, out);
}

// Round 2
// 547.681 us; speedup vs baseline: 1.4686x; 1.4686x over previous
//
#include <hip/hip_runtime.h>
#include <cmath>

namespace {
constexpr int MSTEPS = 50000;
constexpr int NSYN   = 500;
constexpr int NQ4    = 125;    // NSYN / 4
constexpr int NTH    = 1024;
constexpr int TPT    = 49;     // NTH*TPT = 50176 >= MSTEPS
constexpr int CMAX   = (MSTEPS - 1) / TPT;  // last chunk index with valid data (1020)
constexpr int MAXSEG = 2048;   // min physical segment ~450 steps -> ~110 resets; 2048 = huge margin
constexpr double DELTA_D = 1.0e-3;
constexpr double THETA_D = 1.0;
// float32(exp(-1/10)) promoted to double — match the reference's f32 decay constant
constexpr float DECAY_F = 0.90483741803595957311f;
}

// ---------------- Kernel 1: per-timestep weighted row sums ----------------
// sw[i] = sum_j |w_j| * spikes[i][j] ; iw[i] = sum_j vrev_j*|w_j| * spikes[i][j]
// 4 rows per wave, f32 accumulate (error ~1e-6 absolute, harmless vs 4e-3 margin),
// w/vrev loaded once per wave, float4 result store by lane 0.
__global__ __launch_bounds__(256) void k_rowdot(
    const float* __restrict__ spikes,
    const float* __restrict__ w,
    const float* __restrict__ vrev,
    float* __restrict__ swv,
    float* __restrict__ iwv)
{
    const int lane = threadIdx.x & 63;
    const int wv   = threadIdx.x >> 6;
    const int row0 = (blockIdx.x * 4 + wv) * 4;   // 16 rows per block, grid=3125 exact

    const float4* __restrict__ w4 = reinterpret_cast<const float4*>(w);
    const float4* __restrict__ r4 = reinterpret_cast<const float4*>(vrev);

    const int j1 = lane;
    const int j2 = lane + 64;
    const bool has2 = (j2 < NQ4);

    float4 a1 = w4[j1];
    float4 r1 = r4[j1];
    float4 aw1 = make_float4(fabsf(a1.x), fabsf(a1.y), fabsf(a1.z), fabsf(a1.w));
    float4 ar1 = make_float4(aw1.x * r1.x, aw1.y * r1.y, aw1.z * r1.z, aw1.w * r1.w);
    float4 aw2 = make_float4(0.f, 0.f, 0.f, 0.f), ar2 = aw2;
    if (has2) {
        float4 a2 = w4[j2];
        float4 r2 = r4[j2];
        aw2 = make_float4(fabsf(a2.x), fabsf(a2.y), fabsf(a2.z), fabsf(a2.w));
        ar2 = make_float4(aw2.x * r2.x, aw2.y * r2.y, aw2.z * r2.z, aw2.w * r2.w);
    }

    float sp[4], ip[4];
#pragma unroll
    for (int r = 0; r < 4; ++r) {
        const float4* __restrict__ srow =
            reinterpret_cast<const float4*>(spikes + (size_t)(row0 + r) * NSYN);
        float4 s1 = srow[j1];
        float a = s1.x * aw1.x + s1.y * aw1.y + s1.z * aw1.z + s1.w * aw1.w;
        float b = s1.x * ar1.x + s1.y * ar1.y + s1.z * ar1.z + s1.w * ar1.w;
        if (has2) {
            float4 s2 = srow[j2];
            a += s2.x * aw2.x + s2.y * aw2.y + s2.z * aw2.z + s2.w * aw2.w;
            b += s2.x * ar2.x + s2.y * ar2.y + s2.z * ar2.z + s2.w * ar2.w;
        }
        sp[r] = a; ip[r] = b;
    }
#pragma unroll
    for (int d = 32; d > 0; d >>= 1) {
#pragma unroll
        for (int r = 0; r < 4; ++r) {
            sp[r] += __shfl_xor(sp[r], d);
            ip[r] += __shfl_xor(ip[r], d);
        }
    }
    if (lane == 0) {
        *reinterpret_cast<float4*>(swv + row0) = make_float4(sp[0], sp[1], sp[2], sp[3]);
        *reinterpret_cast<float4*>(iwv + row0) = make_float4(ip[0], ip[1], ip[2], ip[3]);
    }
}

// ---------------- Kernel 2: scans + crossing search + parallel fill ----------------
__global__ __launch_bounds__(1024) void k_scan(
    const float* __restrict__ swv,
    const float* __restrict__ iwv,
    double2* __restrict__ pqa,
    float* __restrict__ out)
{
    const double decay = (double)DECAY_F;
    const int tid  = threadIdx.x;
    const int lane = tid & 63;
    const int wv   = tid >> 6;
    const int base = tid * TPT;

    __shared__ double s_a[16], s_b[16], s_c[16];
    __shared__ double s_maxR[NTH];
    __shared__ int    s_bnd[MAXSEG];
    __shared__ double s_bndQ[MAXSEG];
    __shared__ int    s_nseg;

    // ---- Pass A: local (g,i) scan with zero entry ----
    double g = 0.0, ii = 0.0;
    for (int k = 0; k < TPT; ++k) {
        int idx = base + k;
        double s = (idx < MSTEPS) ? (double)swv[idx] : 0.0;
        double t = (idx < MSTEPS) ? (double)iwv[idx] : 0.0;
        g  = (g + s) * decay;
        ii = (ii + t) * decay;
    }
    double dm = 1.0;
    for (int k = 0; k < TPT; ++k) dm *= decay;   // decay^TPT (uniform all threads)

    double m_in = dm, g_in = g, i_in = ii;
#pragma unroll
    for (int d = 1; d < 64; d <<= 1) {
        double pm = __shfl_up(m_in, d);
        double pg = __shfl_up(g_in, d);
        double pi = __shfl_up(i_in, d);
        if (lane >= d) {
            g_in = m_in * pg + g_in;
            i_in = m_in * pi + i_in;
            m_in = pm * m_in;
        }
    }
    if (lane == 63) { s_a[wv] = m_in; s_b[wv] = g_in; s_c[wv] = i_in; }
    __syncthreads();
    if (wv == 0) {
        double wm = (lane < 16) ? s_a[lane] : 1.0;
        double wg = (lane < 16) ? s_b[lane] : 0.0;
        double wi = (lane < 16) ? s_c[lane] : 0.0;
#pragma unroll
        for (int d = 1; d < 16; d <<= 1) {
            double pm = __shfl_up(wm, d);
            double pg = __shfl_up(wg, d);
            double pi = __shfl_up(wi, d);
            if (lane >= d) {
                wg = wm * pg + wg;
                wi = wm * pi + wi;
                wm = pm * wm;
            }
        }
        if (lane < 16) { s_a[lane] = wm; s_b[lane] = wg; s_c[lane] = wi; }
    }
    __syncthreads();
    double em = __shfl_up(m_in, 1), eg = __shfl_up(g_in, 1), ei = __shfl_up(i_in, 1);
    if (lane == 0) { em = 1.0; eg = 0.0; ei = 0.0; }
    if (wv > 0) {
        double qm = s_a[wv - 1], qg = s_b[wv - 1], qi = s_c[wv - 1];
        eg = em * qg + eg;
        ei = em * qi + ei;
        em = qm * em;
    }
    const double gent = eg, ient = ei;
    __syncthreads();   // s_a..c reused below

    // ---- Pass B: local (p, q) with zero entry, then block scan ----
    g = gent; ii = ient;
    double p = 1.0, q = 0.0;
    for (int k = 0; k < TPT; ++k) {
        int idx = base + k;
        double aa = DELTA_D * (1.0 + g);
        double bb = DELTA_D * ii;
        p *= (1.0 - aa);
        q += bb / p;
        double s = (idx < MSTEPS) ? (double)swv[idx] : 0.0;
        double t = (idx < MSTEPS) ? (double)iwv[idx] : 0.0;
        g  = (g + s) * decay;
        ii = (ii + t) * decay;
    }
    double p_in = p, q_in = q;
#pragma unroll
    for (int d = 1; d < 64; d <<= 1) {
        double pp = __shfl_up(p_in, d);
        double pq = __shfl_up(q_in, d);
        if (lane >= d) {
            q_in = pq + q_in / pp;
            p_in = pp * p_in;
        }
    }
    if (lane == 63) { s_a[wv] = p_in; s_b[wv] = q_in; }
    __syncthreads();
    if (wv == 0) {
        double wp = (lane < 16) ? s_a[lane] : 1.0;
        double wq = (lane < 16) ? s_b[lane] : 0.0;
#pragma unroll
        for (int d = 1; d < 16; d <<= 1) {
            double pp = __shfl_up(wp, d);
            double pq = __shfl_up(wq, d);
            if (lane >= d) {
                wq = pq + wq / pp;
                wp = pp * wp;
            }
        }
        if (lane < 16) { s_a[lane] = wp; s_b[lane] = wq; }
    }
    __syncthreads();
    double ep = __shfl_up(p_in, 1), eq = __shfl_up(q_in, 1);
    if (lane == 0) { ep = 1.0; eq = 0.0; }
    if (wv > 0) {
        double ap = s_a[wv - 1], aq = s_b[wv - 1];
        eq = aq + eq / ap;
        ep = ap * ep;
    }

    // ---- Pass C: store global (P_i, Q_i); track conservative per-chunk max of
    //      R_i = Q_i - theta/P_i (+1e-12 relative slack => pruning can never skip
    //      a true crossing; exact re-check below uses the bit-identical expression) ----
    g = gent; ii = ient;
    double P = ep, Q = eq;
    double invPl = 1.0 / ep;
    double maxR = -1.0e308;
    for (int k = 0; k < TPT; ++k) {
        int idx = base + k;
        if (idx < MSTEPS) {
            pqa[idx] = make_double2(P, Q);
            double R = (Q - invPl) + 1.0e-12 * (fabs(Q) + invPl);
            maxR = fmax(maxR, R);
        }
        double aa = DELTA_D * (1.0 + g);
        double bb = DELTA_D * ii;
        double om = 1.0 - aa;
        P *= om;
        Q += bb / P;
        invPl /= om;
        double s = (idx < MSTEPS) ? (double)swv[idx] : 0.0;
        double t = (idx < MSTEPS) ? (double)iwv[idx] : 0.0;
        g  = (g + s) * decay;
        ii = (ii + t) * decay;
    }
    s_maxR[tid] = maxR;
    __threadfence_block();
    __syncthreads();

    // ---- Phase 1 (wave 0 only): segment-hopping crossing search ----
    if (wv == 0) {
        int nseg = 1;
        if (lane == 0) { s_bnd[0] = 0; s_bndQ[0] = 0.0; }
        double Qr = 0.0;
        int pos = 1;
        while (pos < MSTEPS && nseg < MAXSEG) {
            // exact scan of the chunk containing pos (mask i >= pos)
            int c = pos / TPT;
            int i0 = -1;
            {
                int i = c * TPT + lane;
                bool valid = (lane < TPT) && (i >= pos) && (i < MSTEPS);
                double v = -1.0;
                if (valid) { double2 pq = pqa[i]; v = pq.x * (pq.y - Qr); }
                unsigned long long m = __ballot(valid && (v >= THETA_D));
                if (m) i0 = c * TPT + __builtin_ctzll(m);
            }
            while (i0 < 0) {
                // prune: first chunk > c whose maxR (slack-inflated) can cross Qr
                int cnext = -1;
                for (int cb = c + 1; cb <= CMAX; cb += 64) {
                    int cc = cb + lane;
                    bool qy = (cc <= CMAX) && (s_maxR[cc] >= Qr);
                    unsigned long long m = __ballot(qy);
                    if (m) { cnext = cb + __builtin_ctzll(m); break; }
                }
                if (cnext < 0) { pos = MSTEPS; break; }
                c = cnext;
                int i = c * TPT + lane;
                bool valid = (lane < TPT) && (i < MSTEPS);
                double v = -1.0;
                if (valid) { double2 pq = pqa[i]; v = pq.x * (pq.y - Qr); }
                unsigned long long m2 = __ballot(valid && (v >= THETA_D));
                if (m2) i0 = c * TPT + __builtin_ctzll(m2);
                // false positive (slack) -> continue pruning from c+1
            }
            if (i0 < 0) break;          // no further crossing
            int nb = i0 + 1;            // reset lands at nb
            if (nb >= MSTEPS) break;
            double2 pqb = pqa[nb];      // uniform address -> broadcast load
            Qr = pqb.y;
            if (lane == 0) { s_bnd[nseg] = nb; s_bndQ[nseg] = Qr; }
            nseg++;
            pos = nb + 1;
        }
        if (lane == 0) s_nseg = nseg;
    }
    __syncthreads();

    // ---- Phase 2 (all waves): parallel fill ----
    const int nseg = s_nseg;
    if (base < MSTEPS) {
        // binary search: largest seg with bnd[seg] <= base
        int lo = 0, hi = nseg - 1;
        while (lo < hi) {
            int mid = (lo + hi + 1) >> 1;
            if (s_bnd[mid] <= base) lo = mid; else hi = mid - 1;
        }
        int seg = lo;
        double Qr = s_bndQ[seg];
        int nextb = (seg + 1 < nseg) ? s_bnd[seg + 1] : MSTEPS;
        for (int k = 0; k < TPT; ++k) {
            int i = base + k;
            if (i >= MSTEPS) break;
            if (i >= nextb) {
                seg++;
                Qr = s_bndQ[seg];
                nextb = (seg + 1 < nseg) ? s_bnd[seg + 1] : MSTEPS;
            }
            if (i == s_bnd[seg]) {
                out[i] = 0.0f;
            } else {
                double2 pq = pqa[i];
                out[i] = (float)(pq.x * (pq.y - Qr));
            }
        }
    }
}

extern "C" void kernel_launch(void* const* d_in, const int* in_sizes, int n_in,
                              void* d_out, int out_size, void* d_ws, size_t ws_size,
                              hipStream_t stream) {
    const float* spikes = (const float*)d_in[0];
    const float* w      = (const float*)d_in[1];
    const float* vrev   = (const float*)d_in[2];
    float* out = (float*)d_out;

    // workspace layout: sw[50176] f32 | iw[50176] f32 | PQ[50000] double2
    float* swv = (float*)d_ws;
    float* iwv = swv + (NTH * TPT);
    double2* pqa = (double2*)((char*)d_ws + (size_t)2 * NTH * TPT * sizeof(float));

    hipLaunchKernelGGL(k_rowdot, dim3(MSTEPS / 16), dim3(256), 0, stream,
                       spikes, w, vrev, swv, iwv);
    hipLaunchKernelGGL(k_scan, dim3(1), dim3(NTH), 0, stream,
                       swv, iwv, pqa, out);
}

// Round 3
// 338.029 us; speedup vs baseline: 2.3795x; 1.6202x over previous
//
#include <hip/hip_runtime.h>
#include <cmath>

namespace {
constexpr int MSTEPS = 50000;
constexpr int NSYN   = 500;
constexpr int NQ4    = 125;    // NSYN / 4
constexpr int NTH    = 1024;
constexpr int TPT    = 49;     // NTH*TPT = 50176 >= MSTEPS
constexpr int SLOTS  = NTH * TPT;            // 50176
constexpr int CMAX   = (MSTEPS - 1) / TPT;   // 1020
constexpr int MAXSEG = 2048;
constexpr double DELTA_D = 1.0e-3;
constexpr double THETA_D = 1.0;
// float32(exp(-1/10)) promoted to double — match the reference's f32 decay constant
constexpr float DECAY_F = 0.90483741803595957311f;
}

// ---------------- Kernel 1: per-timestep weighted row sums ----------------
// sw[i] = sum_j |w_j|*spikes[i][j] ; iw[i] = sum_j vrev_j*|w_j|*spikes[i][j]
// 8 rows per wave (2x memory-level parallelism). Results stored TRANSPOSED:
// row i -> addr (i%49)*1024 + i/49, so k_scan's per-thread chunk loops become
// wave-coalesced (lane-consecutive addresses at each k step).
__global__ __launch_bounds__(256) void k_rowdot(
    const float* __restrict__ spikes,
    const float* __restrict__ w,
    const float* __restrict__ vrev,
    float* __restrict__ swv,
    float* __restrict__ iwv)
{
    const int lane = threadIdx.x & 63;
    const int wv   = threadIdx.x >> 6;
    const int row0 = (blockIdx.x * 4 + wv) * 8;   // 32 rows/block; 50000 % 8 == 0
    if (row0 >= MSTEPS) return;

    const float4* __restrict__ w4 = reinterpret_cast<const float4*>(w);
    const float4* __restrict__ r4 = reinterpret_cast<const float4*>(vrev);

    const int j1 = lane;
    const int j2 = lane + 64;
    const bool has2 = (j2 < NQ4);   // lanes 0..60

    float4 a1 = w4[j1];
    float4 r1 = r4[j1];
    float4 aw1 = make_float4(fabsf(a1.x), fabsf(a1.y), fabsf(a1.z), fabsf(a1.w));
    float4 ar1 = make_float4(aw1.x * r1.x, aw1.y * r1.y, aw1.z * r1.z, aw1.w * r1.w);
    float4 aw2 = make_float4(0.f, 0.f, 0.f, 0.f), ar2 = aw2;
    if (has2) {
        float4 a2 = w4[j2];
        float4 r2 = r4[j2];
        aw2 = make_float4(fabsf(a2.x), fabsf(a2.y), fabsf(a2.z), fabsf(a2.w));
        ar2 = make_float4(aw2.x * r2.x, aw2.y * r2.y, aw2.z * r2.z, aw2.w * r2.w);
    }

    float4 s1[8], s2[8];
#pragma unroll
    for (int r = 0; r < 8; ++r) {
        const float4* __restrict__ srow =
            reinterpret_cast<const float4*>(spikes + (size_t)(row0 + r) * NSYN);
        s1[r] = srow[j1];
        if (has2) s2[r] = srow[j2];
    }
    float sp[8], ip[8];
#pragma unroll
    for (int r = 0; r < 8; ++r) {
        float a = s1[r].x * aw1.x + s1[r].y * aw1.y + s1[r].z * aw1.z + s1[r].w * aw1.w;
        float b = s1[r].x * ar1.x + s1[r].y * ar1.y + s1[r].z * ar1.z + s1[r].w * ar1.w;
        if (has2) {
            a += s2[r].x * aw2.x + s2[r].y * aw2.y + s2[r].z * aw2.z + s2[r].w * aw2.w;
            b += s2[r].x * ar2.x + s2[r].y * ar2.y + s2[r].z * ar2.z + s2[r].w * ar2.w;
        }
        sp[r] = a; ip[r] = b;
    }
#pragma unroll
    for (int d = 32; d > 0; d >>= 1) {
#pragma unroll
        for (int r = 0; r < 8; ++r) {
            sp[r] += __shfl_xor(sp[r], d);
            ip[r] += __shfl_xor(ip[r], d);
        }
    }
    if (lane == 0) {
#pragma unroll
        for (int r = 0; r < 8; ++r) {
            int rr = row0 + r;
            int t  = rr / TPT;
            int k  = rr - t * TPT;
            int a  = k * NTH + t;
            swv[a] = sp[r];
            iwv[a] = ip[r];
        }
    }
}

// ---------------- Kernel 2: scans + crossing search + parallel fill ----------------
// All per-thread chunk traffic uses the transposed layout (addr = k*1024 + tid)
// -> coalesced. pqa stores LOCAL (p,q); global (P,Q) = (ep*p, eq + q/ep) applied
// on the fly with per-thread entries (registers for own chunk, LDS for search).
__global__ __launch_bounds__(1024) void k_scan(
    const float* __restrict__ swv,
    const float* __restrict__ iwv,
    double2* __restrict__ pqa,
    float* __restrict__ out)
{
    const double decay = (double)DECAY_F;
    const int tid  = threadIdx.x;
    const int lane = tid & 63;
    const int wv   = tid >> 6;
    const int base = tid * TPT;

    __shared__ double s_a[16], s_b[16], s_c[16];
    __shared__ double s_maxR[NTH];
    __shared__ double s_eP[NTH], s_eQ[NTH], s_eI[NTH];
    __shared__ int    s_bnd[MAXSEG];
    __shared__ double s_bndQ[MAXSEG];
    __shared__ int    s_nseg;

    // ---- Pass A: local (g,i) affine scan aggregates (coalesced loads) ----
    double g = 0.0, ii = 0.0;
    for (int k = 0; k < TPT; ++k) {
        int idx = base + k;
        int a   = k * NTH + tid;
        double s = (idx < MSTEPS) ? (double)swv[a] : 0.0;
        double t = (idx < MSTEPS) ? (double)iwv[a] : 0.0;
        g  = (g + s) * decay;
        ii = (ii + t) * decay;
    }
    double dm = 1.0;
    for (int k = 0; k < TPT; ++k) dm *= decay;   // decay^TPT (uniform)

    double m_in = dm, g_in = g, i_in = ii;
#pragma unroll
    for (int d = 1; d < 64; d <<= 1) {
        double pm = __shfl_up(m_in, d);
        double pg = __shfl_up(g_in, d);
        double pi = __shfl_up(i_in, d);
        if (lane >= d) {
            g_in = m_in * pg + g_in;
            i_in = m_in * pi + i_in;
            m_in = pm * m_in;
        }
    }
    if (lane == 63) { s_a[wv] = m_in; s_b[wv] = g_in; s_c[wv] = i_in; }
    __syncthreads();
    if (wv == 0) {
        double wm = (lane < 16) ? s_a[lane] : 1.0;
        double wg = (lane < 16) ? s_b[lane] : 0.0;
        double wi = (lane < 16) ? s_c[lane] : 0.0;
#pragma unroll
        for (int d = 1; d < 16; d <<= 1) {
            double pm = __shfl_up(wm, d);
            double pg = __shfl_up(wg, d);
            double pi = __shfl_up(wi, d);
            if (lane >= d) {
                wg = wm * pg + wg;
                wi = wm * pi + wi;
                wm = pm * wm;
            }
        }
        if (lane < 16) { s_a[lane] = wm; s_b[lane] = wg; s_c[lane] = wi; }
    }
    __syncthreads();
    double em = __shfl_up(m_in, 1), eg = __shfl_up(g_in, 1), ei = __shfl_up(i_in, 1);
    if (lane == 0) { em = 1.0; eg = 0.0; ei = 0.0; }
    if (wv > 0) {
        double qm = s_a[wv - 1], qg = s_b[wv - 1], qi = s_c[wv - 1];
        eg = em * qg + eg;
        ei = em * qi + ei;
        em = qm * em;
    }
    const double gent = eg, ient = ei;
    __syncthreads();   // s_a..c reused below

    // ---- Pass B: local (p,q) per element stored to pqa (coalesced);
    //      track mx = max_k (q_loc - theta/p_loc) for the prune bound ----
    g = gent; ii = ient;
    double p = 1.0, q = 0.0, ipl = 1.0;
    double mx = -1.0e308;
    for (int k = 0; k < TPT; ++k) {
        int idx = base + k;
        int a   = k * NTH + tid;
        pqa[a] = make_double2(p, q);               // state ENTERING element idx
        if (idx < MSTEPS) mx = fmax(mx, q - THETA_D * ipl);
        double s = (idx < MSTEPS) ? (double)swv[a] : 0.0;
        double t = (idx < MSTEPS) ? (double)iwv[a] : 0.0;
        double aa = DELTA_D * (1.0 + g);
        double bb = DELTA_D * ii;
        double om = 1.0 - aa;
        p  *= om;
        ipl /= om;
        q  += bb * ipl;
        g  = (g + s) * decay;
        ii = (ii + t) * decay;
    }
    double p_in = p, q_in = q;
#pragma unroll
    for (int d = 1; d < 64; d <<= 1) {
        double pp = __shfl_up(p_in, d);
        double pq = __shfl_up(q_in, d);
        if (lane >= d) {
            q_in = pq + q_in / pp;
            p_in = pp * p_in;
        }
    }
    if (lane == 63) { s_a[wv] = p_in; s_b[wv] = q_in; }
    __syncthreads();
    if (wv == 0) {
        double wp = (lane < 16) ? s_a[lane] : 1.0;
        double wq = (lane < 16) ? s_b[lane] : 0.0;
#pragma unroll
        for (int d = 1; d < 16; d <<= 1) {
            double pp = __shfl_up(wp, d);
            double pq = __shfl_up(wq, d);
            if (lane >= d) {
                wq = pq + wq / pp;
                wp = pp * wp;
            }
        }
        if (lane < 16) { s_a[lane] = wp; s_b[lane] = wq; }
    }
    __syncthreads();
    double ep = __shfl_up(p_in, 1), eq = __shfl_up(q_in, 1);
    if (lane == 0) { ep = 1.0; eq = 0.0; }
    if (wv > 0) {
        double ap = s_a[wv - 1], aq = s_b[wv - 1];
        eq = aq + eq / ap;
        ep = ap * ep;
    }
    const double iep = 1.0 / ep;

    // prune bound: R = max_i (Q_i - theta/P_i) over this chunk, +1e-12 rel slack
    {
        double R = eq + iep * mx;
        s_maxR[tid] = R + 1.0e-12 * fabs(R) + 1.0e-250;
        s_eP[tid] = ep; s_eQ[tid] = eq; s_eI[tid] = iep;
    }
    __threadfence_block();
    __syncthreads();

    // ---- Phase 1 (wave 0): segment-hopping crossing search ----
    if (wv == 0) {
        int nseg = 1;
        if (lane == 0) { s_bnd[0] = 0; s_bndQ[0] = 0.0; }
        double Qr = 0.0;
        int pos = 1;
        while (pos < MSTEPS && nseg < MAXSEG) {
            int c = pos / TPT;
            int i0 = -1;
            {
                int i = c * TPT + lane;
                bool valid = (lane < TPT) && (i >= pos) && (i < MSTEPS);
                double v = -1.0;
                if (valid) {
                    double2 pl = pqa[lane * NTH + c];
                    double P = s_eP[c] * pl.x;
                    double Q = s_eQ[c] + s_eI[c] * pl.y;
                    v = P * (Q - Qr);
                }
                unsigned long long m = __ballot(valid && (v >= THETA_D));
                if (m) i0 = c * TPT + __builtin_ctzll(m);
            }
            while (i0 < 0) {
                int cnext = -1;
                for (int cb = c + 1; cb <= CMAX; cb += 64) {
                    int cc = cb + lane;
                    bool qy = (cc <= CMAX) && (s_maxR[cc] >= Qr);
                    unsigned long long m = __ballot(qy);
                    if (m) { cnext = cb + __builtin_ctzll(m); break; }
                }
                if (cnext < 0) { pos = MSTEPS; break; }
                c = cnext;
                int i = c * TPT + lane;
                bool valid = (lane < TPT) && (i < MSTEPS);
                double v = -1.0;
                if (valid) {
                    double2 pl = pqa[lane * NTH + c];
                    double P = s_eP[c] * pl.x;
                    double Q = s_eQ[c] + s_eI[c] * pl.y;
                    v = P * (Q - Qr);
                }
                unsigned long long m2 = __ballot(valid && (v >= THETA_D));
                if (m2) i0 = c * TPT + __builtin_ctzll(m2);
                // slack false positive -> keep pruning from c+1
            }
            if (i0 < 0) break;
            int nb = i0 + 1;
            if (nb >= MSTEPS) break;
            int tb = nb / TPT, kb = nb - tb * TPT;
            double2 pb = pqa[kb * NTH + tb];          // uniform -> broadcast
            Qr = s_eQ[tb] + s_eI[tb] * pb.y;
            if (lane == 0) { s_bnd[nseg] = nb; s_bndQ[nseg] = Qr; }
            nseg++;
            pos = nb + 1;
        }
        if (lane == 0) s_nseg = nseg;
    }
    __syncthreads();

    // ---- Phase 2 (all waves): parallel fill; pqa reads coalesced ----
    const int nseg = s_nseg;
    if (base < MSTEPS) {
        int lo = 0, hi = nseg - 1;
        while (lo < hi) {
            int mid = (lo + hi + 1) >> 1;
            if (s_bnd[mid] <= base) lo = mid; else hi = mid - 1;
        }
        int seg = lo;
        double Qr = s_bndQ[seg];
        int nextb = (seg + 1 < nseg) ? s_bnd[seg + 1] : MSTEPS;
        for (int k = 0; k < TPT; ++k) {
            int i = base + k;
            if (i >= MSTEPS) break;
            if (i >= nextb) {
                seg++;
                Qr = s_bndQ[seg];
                nextb = (seg + 1 < nseg) ? s_bnd[seg + 1] : MSTEPS;
            }
            if (i == s_bnd[seg]) {
                out[i] = 0.0f;
            } else {
                double2 pl = pqa[k * NTH + tid];
                double P = ep * pl.x;
                double Q = eq + iep * pl.y;
                out[i] = (float)(P * (Q - Qr));
            }
        }
    }
}

extern "C" void kernel_launch(void* const* d_in, const int* in_sizes, int n_in,
                              void* d_out, int out_size, void* d_ws, size_t ws_size,
                              hipStream_t stream) {
    const float* spikes = (const float*)d_in[0];
    const float* w      = (const float*)d_in[1];
    const float* vrev   = (const float*)d_in[2];
    float* out = (float*)d_out;

    // workspace: swv_t f32[50176] | iwv_t f32[50176] | pqa double2[50176]
    float* swv = (float*)d_ws;
    float* iwv = swv + SLOTS;
    double2* pqa = (double2*)((char*)d_ws + (size_t)2 * SLOTS * sizeof(float));

    hipLaunchKernelGGL(k_rowdot, dim3((MSTEPS + 31) / 32), dim3(256), 0, stream,
                       spikes, w, vrev, swv, iwv);
    hipLaunchKernelGGL(k_scan, dim3(1), dim3(NTH), 0, stream,
                       swv, iwv, pqa, out);
}